// Round 8
// baseline (438.222 us; speedup 1.0000x reference)
//
#include <hip/hip_runtime.h>
#include <hip/hip_cooperative_groups.h>
#include <stdint.h>

namespace cg = cooperative_groups;

#define NB 8
#define NN 107136
#define NPAIR (NN / 2)       // 53568
#define SEGS 32
#define CHUNK (NPAIR / SEGS) // 1674
#define PRE 2048
#define POST 128
#define CAP 4096
#define HBINS 128            // 16-bit key bins restricted to s in [0.5, 1)
#define KEYBASE 0xBF00u
#define SCORE_TH 0.05f
#define NSCAN 512            // boxes covered by the suppression-bit mask

// ---------------- ws layout (bytes) ----------------
static constexpr size_t OFF_HP   = 0;                              // partial hists, 32 segs
static constexpr size_t SZ_HP    = (size_t)NB * SEGS * HBINS * 4;  // 128 KiB
static constexpr size_t OFF_CNT  = OFF_HP + SZ_HP;                 // 8 x 64 u32
static constexpr size_t SZ_CNT   = (size_t)NB * 64 * 4;
static constexpr size_t OFF_CAND = OFF_CNT + SZ_CNT + 256;
static constexpr size_t SZ_CAND  = (size_t)NB * CAP * 8;
static constexpr size_t OFF_RANK = OFF_CAND + SZ_CAND;             // rank accumulators
static constexpr size_t SZ_RANK  = (size_t)NB * CAP * 4;

// Single cooperative kernel: softmax+hist | findT+compact | rank | decode+mask+NMS+out
// grid (32, 8) x 1024 threads; 97 KB LDS -> 1 block/CU, 256 co-resident blocks.
__global__ void __launch_bounds__(1024, 1) k_all(
        const float* __restrict__ box_preds, const float* __restrict__ cls,
        const float* __restrict__ dir_preds, const float* __restrict__ anchors,
        float* __restrict__ out,
        uint32_t* __restrict__ hp, uint32_t* __restrict__ counts,
        uint64_t* __restrict__ cand, uint32_t* __restrict__ rankArr)
{
    cg::grid_group grid = cg::this_grid();
    const int bx = blockIdx.x, by = blockIdx.y;
    const int t = threadIdx.x;
    const int lane = t & 63, wid = t >> 6;
    const int g = by * 32 + bx;                   // linear block id 0..255

    __shared__ uint32_t lh[HBINS];
    __shared__ uint32_t lcnt;
    __shared__ uint32_t gbaseSh;
    __shared__ uint32_t wbase[16];
    __shared__ float4   sbb[PRE];                 // 32 KiB
    __shared__ float    sar[PRE];                 // 8 KiB
    __shared__ uint64_t keyOrd[PRE];              // 16 KiB
    __shared__ uint64_t smask[NSCAN * 8];         // 32 KiB
    __shared__ uint64_t sKeys[1024];              // 8 KiB (rank j-tile)
    __shared__ int      keptIdx[POST];
    __shared__ int      keptCountSh;

    // ================= phase A: softmax (scores stay in REGISTERS) + partial hist
    if (t < HBINS) lh[t] = 0u;
    if (bx == 0 && t == 0) counts[(size_t)by * 64] = 0u;
    { int idx = g * 1024 + t; if (idx < NB * CAP) rankArr[idx] = 0u; }
    __syncthreads();

    const float4* cp = (const float4*)cls + (size_t)by * NPAIR;
    const int base = bx * CHUNK;                  // pair index within batch
    const bool has1 = (t < CHUNK - 1024);         // 650 threads carry a 2nd pair
    float2 s0, s1 = make_float2(-1.f, -1.f);
    {
        float4 c = cp[base + t];
        float m0 = fmaxf(c.x, c.y);
        s0.x = __fdiv_rn(expf(__fsub_rn(c.y, m0)),
                         __fadd_rn(expf(__fsub_rn(c.x, m0)), expf(__fsub_rn(c.y, m0))));
        float m1 = fmaxf(c.z, c.w);
        s0.y = __fdiv_rn(expf(__fsub_rn(c.w, m1)),
                         __fadd_rn(expf(__fsub_rn(c.z, m1)), expf(__fsub_rn(c.w, m1))));
        if (s0.x >= 0.5f) {
            uint32_t bin = ((__float_as_uint(s0.x) >> 16) | 0x8000u) - KEYBASE;
            if (bin > 127u) bin = 127u;
            atomicAdd(&lh[bin], 1u);
        }
        if (s0.y >= 0.5f) {
            uint32_t bin = ((__float_as_uint(s0.y) >> 16) | 0x8000u) - KEYBASE;
            if (bin > 127u) bin = 127u;
            atomicAdd(&lh[bin], 1u);
        }
    }
    if (has1) {
        float4 c = cp[base + 1024 + t];
        float m0 = fmaxf(c.x, c.y);
        s1.x = __fdiv_rn(expf(__fsub_rn(c.y, m0)),
                         __fadd_rn(expf(__fsub_rn(c.x, m0)), expf(__fsub_rn(c.y, m0))));
        float m1 = fmaxf(c.z, c.w);
        s1.y = __fdiv_rn(expf(__fsub_rn(c.w, m1)),
                         __fadd_rn(expf(__fsub_rn(c.z, m1)), expf(__fsub_rn(c.w, m1))));
        if (s1.x >= 0.5f) {
            uint32_t bin = ((__float_as_uint(s1.x) >> 16) | 0x8000u) - KEYBASE;
            if (bin > 127u) bin = 127u;
            atomicAdd(&lh[bin], 1u);
        }
        if (s1.y >= 0.5f) {
            uint32_t bin = ((__float_as_uint(s1.y) >> 16) | 0x8000u) - KEYBASE;
            if (bin > 127u) bin = 127u;
            atomicAdd(&lh[bin], 1u);
        }
    }
    __syncthreads();
    if (t < HBINS) hp[((size_t)by * SEGS + bx) * HBINS + t] = lh[t];

    __threadfence();
    grid.sync();

    // ================= phase C: wave-redundant findT + compact (scores from regs)
    uint32_t Tb;
    {
        const uint32_t* hb = hp + (size_t)by * SEGS * HBINS;
        uint32_t h0 = 0, h1 = 0;
#pragma unroll 8
        for (int sg = 0; sg < SEGS; sg++) {
            h0 += hb[sg * HBINS + 2 * lane];
            h1 += hb[sg * HBINS + 2 * lane + 1];
        }
        uint32_t v = h0 + h1;
        for (int off = 1; off < 64; off <<= 1) {
            uint32_t u = __shfl_down(v, off);
            if (lane + off >= 64) u = 0u;
            v += u;
        }
        uint32_t total = __shfl(v, 0);
        int cbin = -1;
        if (v - h0 >= PRE) cbin = 2 * lane + 1;
        else if (v >= PRE) cbin = 2 * lane;
        for (int off = 32; off > 0; off >>= 1) cbin = max(cbin, __shfl_xor(cbin, off));
        Tb = (total >= PRE && cbin >= 0) ? (KEYBASE + (uint32_t)cbin) : 0u;
    }
    uint32_t k0 = __float_as_uint(s0.x) | 0x80000000u;
    uint32_t k1 = __float_as_uint(s0.y) | 0x80000000u;
    uint32_t k2 = __float_as_uint(s1.x) | 0x80000000u;
    uint32_t k3 = __float_as_uint(s1.y) | 0x80000000u;
    bool p0 = (s0.x >= SCORE_TH) && ((k0 >> 16) >= Tb);
    bool p1 = (s0.y >= SCORE_TH) && ((k1 >> 16) >= Tb);
    bool p2 = has1 && (s1.x >= SCORE_TH) && ((k2 >> 16) >= Tb);
    bool p3 = has1 && (s1.y >= SCORE_TH) && ((k3 >> 16) >= Tb);
    uint64_t bal0 = __ballot(p0), bal1 = __ballot(p1);
    uint64_t bal2 = __ballot(p2), bal3 = __ballot(p3);
    uint32_t n0 = (uint32_t)__popcll(bal0), n1 = (uint32_t)__popcll(bal1);
    uint32_t n2 = (uint32_t)__popcll(bal2), n3 = (uint32_t)__popcll(bal3);
    uint32_t wcnt = n0 + n1 + n2 + n3;
    uint64_t below = (1ull << lane) - 1ull;
    uint32_t o0 = (uint32_t)__popcll(bal0 & below);
    uint32_t o1 = n0 + (uint32_t)__popcll(bal1 & below);
    uint32_t o2 = n0 + n1 + (uint32_t)__popcll(bal2 & below);
    uint32_t o3 = n0 + n1 + n2 + (uint32_t)__popcll(bal3 & below);
    if (t == 0) lcnt = 0u;
    __syncthreads();
    if (lane == 0 && wcnt) wbase[wid] = atomicAdd(&lcnt, wcnt);
    __syncthreads();
    if (t == 0 && lcnt) gbaseSh = atomicAdd(&counts[(size_t)by * 64], lcnt);
    __syncthreads();
    if (p0 | p1 | p2 | p3) {
        uint32_t bslot = gbaseSh + wbase[wid];
        uint64_t* cb = cand + (size_t)by * CAP;
        uint32_t e0 = 2u * (uint32_t)(base + t);
        uint32_t e2 = 2u * (uint32_t)(base + 1024 + t);
        if (p0) { uint32_t s = bslot + o0; if (s < CAP) cb[s] = ((uint64_t)k0 << 32) | (uint64_t)(0xFFFFFFFFu - e0); }
        if (p1) { uint32_t s = bslot + o1; if (s < CAP) cb[s] = ((uint64_t)k1 << 32) | (uint64_t)(0xFFFFFFFFu - (e0 + 1u)); }
        if (p2) { uint32_t s = bslot + o2; if (s < CAP) cb[s] = ((uint64_t)k2 << 32) | (uint64_t)(0xFFFFFFFFu - e2); }
        if (p3) { uint32_t s = bslot + o3; if (s < CAP) cb[s] = ((uint64_t)k3 << 32) | (uint64_t)(0xFFFFFFFFu - (e2 + 1u)); }
    }

    __threadfence();
    grid.sync();

    // ================= phase D: rank via 1024x1024 tiles (128 active blocks)
    if (g < 128) {
        int b = g >> 4, tile = g & 15, it = tile >> 2, jt = tile & 3;
        int m = (int)counts[(size_t)b * 64]; if (m > CAP) m = CAP;
        int i0 = it * 1024, j0 = jt * 1024;
        if (i0 < m && j0 < m) {                   // block-uniform
            const uint64_t* cb = cand + (size_t)b * CAP;
            int jj = j0 + t;
            sKeys[t] = (jj < m) ? cb[jj] : 0ull;  // 0 is rank-neutral (real keys have MSB set)
            __syncthreads();
            int i = i0 + t;
            if (i < m) {
                uint64_t mykey = cb[i];
                uint32_t r = 0;
                int jl = m - j0; if (jl > 1024) jl = 1024;
#pragma unroll 8
                for (int j = 0; j < jl; j++)
                    r += (sKeys[j] > mykey) ? 1u : 0u;
                if (r) atomicAdd(&rankArr[(size_t)b * CAP + i], r);
            }
        }
    }

    __threadfence();
    grid.sync();

    // ================= phase EFG: decode -> mask -> bit-scan NMS -> finalize (8 blocks)
    if (g < NB) {
        const int b = g;
        int m = (int)counts[(size_t)b * 64]; if (m > CAP) m = CAP;
        int Mv = (m > PRE) ? PRE : m;
        const uint64_t* cb = cand + (size_t)b * CAP;

        // gather + standup-decode every candidate with rank < PRE into sorted LDS slot
        for (int i = t; i < m; i += 1024) {
            uint32_t r = rankArr[(size_t)b * CAP + i];
            if (r >= PRE) continue;
            uint64_t key = cb[i];
            uint32_t idx = 0xFFFFFFFFu - (uint32_t)(key & 0xFFFFFFFFull);
            const float* bp = box_preds + ((size_t)b * NN + idx) * 7;
            const float* an = anchors + ((size_t)b * NN + idx) * 7;
            float xa = an[0], ya = an[1], wa = an[3], la = an[4], ra = an[6];
            float xt = bp[0], yt = bp[1], wt = bp[3], lt = bp[4], rt = bp[6];
            float diag = sqrtf(__fadd_rn(__fmul_rn(la, la), __fmul_rn(wa, wa)));
            float xg = __fadd_rn(__fmul_rn(xt, diag), xa);
            float yg = __fadd_rn(__fmul_rn(yt, diag), ya);
            float lg = __fmul_rn(expf(lt), la);
            float wg = __fmul_rn(expf(wt), wa);
            float rg = __fadd_rn(rt, ra);
            float cc = fabsf(cosf(rg)), ss = fabsf(sinf(rg));
            float hx = __fmul_rn(0.5f, __fadd_rn(__fmul_rn(wg, cc), __fmul_rn(lg, ss)));
            float hy = __fmul_rn(0.5f, __fadd_rn(__fmul_rn(wg, ss), __fmul_rn(lg, cc)));
            float x1 = __fsub_rn(xg, hx), y1 = __fsub_rn(yg, hy);
            float x2 = __fadd_rn(xg, hx), y2 = __fadd_rn(yg, hy);
            sbb[r] = make_float4(x1, y1, x2, y2);
            sar[r] = __fmul_rn(__fsub_rn(x2, x1), __fsub_rn(y2, y1));
            keyOrd[r] = key;
        }
        __syncthreads();

        // suppression-bit mask for first NSCAN ranked boxes (bits j>=Mv never read)
        int lim = (Mv < NSCAN) ? Mv : NSCAN;
        for (int i = wid; i < lim; i += 16) {
            float4 ci = sbb[i]; float ai = sar[i];
#pragma unroll
            for (int wd = 0; wd < 8; wd++) {
                int j = wd * 64 + lane;
                float4 cj = sbb[j]; float aj = sar[j];
                float ix = fmaxf(0.f, __fsub_rn(fminf(ci.z, cj.z), fmaxf(ci.x, cj.x)));
                float iy = fmaxf(0.f, __fsub_rn(fminf(ci.w, cj.w), fmaxf(ci.y, cj.y)));
                float inter = __fmul_rn(ix, iy);
                float den = fmaxf(__fsub_rn(__fadd_rn(ai, aj), inter), 1e-8f);
                bool sup = (j > i) && (inter > __fmul_rn(0.5f, den));
                uint64_t bal = __ballot(sup);
                if (lane == 0) smask[i * 8 + wd] = bal;
            }
        }
        __syncthreads();

        // wave-0 bit-scan (register/ballot only; LDS row OR on keeps)
        if (t < 64) {
            uint64_t removedW = 0ull;             // lane w<8 holds removed word w
            int kc = 0, i = 0;
            for (; i < lim && kc < POST; i++) {
                uint64_t mrow = (lane < 8) ? smask[i * 8 + lane] : 0ull;
                int word = i >> 6;
                bool mybit = (lane == word) && (((removedW >> (i & 63)) & 1ull) != 0ull);
                if (__ballot(mybit) == 0ull) {
                    if (lane == 0) keptIdx[kc] = i;
                    kc++;
                    removedW |= mrow;
                }
            }
            // fallback past the mask window (rare; direct IoU, exact greedy semantics)
            if (kc < POST && Mv > NSCAN) {
                float ax1 = 1e30f, ay1 = 1e30f, ax2 = 1e30f, ay2 = 1e30f, aar = 0.f;
                float bx1 = 1e30f, by1 = 1e30f, bx2 = 1e30f, by2 = 1e30f, bar = 0.f;
                if (lane < kc) {
                    int ki = keptIdx[lane]; float4 cc = sbb[ki];
                    ax1 = cc.x; ay1 = cc.y; ax2 = cc.z; ay2 = cc.w; aar = sar[ki];
                }
                if (lane + 64 < kc) {
                    int ki = keptIdx[lane + 64]; float4 cc = sbb[ki];
                    bx1 = cc.x; by1 = cc.y; bx2 = cc.z; by2 = cc.w; bar = sar[ki];
                }
                for (; i < Mv && kc < POST; i++) {
                    float4 cc = sbb[i];
                    float ca = sar[i];
                    float ix = fmaxf(0.f, __fsub_rn(fminf(ax2, cc.z), fmaxf(ax1, cc.x)));
                    float iy = fmaxf(0.f, __fsub_rn(fminf(ay2, cc.w), fmaxf(ay1, cc.y)));
                    float inter = __fmul_rn(ix, iy);
                    float den = fmaxf(__fsub_rn(__fadd_rn(aar, ca), inter), 1e-8f);
                    bool sup = inter > __fmul_rn(0.5f, den);
                    ix = fmaxf(0.f, __fsub_rn(fminf(bx2, cc.z), fmaxf(bx1, cc.x)));
                    iy = fmaxf(0.f, __fsub_rn(fminf(by2, cc.w), fmaxf(by1, cc.y)));
                    inter = __fmul_rn(ix, iy);
                    den = fmaxf(__fsub_rn(__fadd_rn(bar, ca), inter), 1e-8f);
                    sup = sup || (inter > __fmul_rn(0.5f, den));
                    if (__ballot(sup) == 0ull) {
                        if (lane == 0) keptIdx[kc] = i;
                        if (kc < 64) {
                            if (lane == kc) { ax1 = cc.x; ay1 = cc.y; ax2 = cc.z; ay2 = cc.w; aar = ca; }
                        } else {
                            if (lane == kc - 64) { bx1 = cc.x; by1 = cc.y; bx2 = cc.z; by2 = cc.w; bar = ca; }
                        }
                        kc++;
                    }
                }
            }
            if (lane == 0) keptCountSh = kc;
        }
        __syncthreads();

        // finalize: re-decode the kept boxes (bit-identical op sequence) and emit
        int kc = keptCountSh;
        if (t < POST) {
            size_t ob = (size_t)b * POST + t;
            float box[7] = {0.f, 0.f, 0.f, 0.f, 0.f, 0.f, 0.f};
            float sc = 0.f, mk = 0.f;
            if (t < kc) {
                uint64_t key = keyOrd[keptIdx[t]];
                float s = __uint_as_float((uint32_t)(key >> 32) & 0x7FFFFFFFu);
                uint32_t idx = 0xFFFFFFFFu - (uint32_t)(key & 0xFFFFFFFFull);
                const float* bp = box_preds + ((size_t)b * NN + idx) * 7;
                const float* an = anchors + ((size_t)b * NN + idx) * 7;
                float xa = an[0], ya = an[1], za = an[2], wa = an[3], la = an[4], ha = an[5], ra = an[6];
                float xt = bp[0], yt = bp[1], zt = bp[2], wt = bp[3], lt = bp[4], ht = bp[5], rt = bp[6];
                float za2  = __fadd_rn(za, __fmul_rn(ha, 0.5f));
                float diag = sqrtf(__fadd_rn(__fmul_rn(la, la), __fmul_rn(wa, wa)));
                float xg = __fadd_rn(__fmul_rn(xt, diag), xa);
                float yg = __fadd_rn(__fmul_rn(yt, diag), ya);
                float zg = __fadd_rn(__fmul_rn(zt, ha), za2);
                float lg = __fmul_rn(expf(lt), la);
                float wg = __fmul_rn(expf(wt), wa);
                float hg = __fmul_rn(expf(ht), ha);
                float rg = __fadd_rn(rt, ra);
                zg = __fsub_rn(zg, __fmul_rn(hg, 0.5f));
                float d0 = dir_preds[((size_t)b * NN + idx) * 2 + 0];
                float d1 = dir_preds[((size_t)b * NN + idx) * 2 + 1];
                float label = (d1 > d0) ? 1.0f : 0.0f;
                const float period = 3.14159265358979323846f;
                float dir_rot = __fsub_rn(rg, __fmul_rn(floorf(__fdiv_rn(rg, period)), period));
                float nr = __fadd_rn(dir_rot, __fmul_rn(period, label));
                bool in_range = (xg >= 0.0f) && (yg >= -39.68f) && (zg >= -5.0f) &&
                                (xg <= 69.12f) && (yg <= 39.68f) && (zg <= 5.0f);
                if (in_range) {
                    box[0] = xg; box[1] = yg; box[2] = zg;
                    box[3] = wg; box[4] = lg; box[5] = hg; box[6] = nr;
                    sc = s; mk = 1.f;
                }
            }
            float* out_b = out;
            float* out_s = out + 7168;
            float* out_l = out + 8192;
            float* out_m = out + 9216;
            for (int c = 0; c < 7; c++) out_b[ob * 7 + c] = box[c];
            out_s[ob] = sc;
            out_l[ob] = 0.f;
            out_m[ob] = mk;
        }
    }
}

extern "C" void kernel_launch(void* const* d_in, const int* in_sizes, int n_in,
                              void* d_out, int out_size, void* d_ws, size_t ws_size,
                              hipStream_t stream) {
    const float* box_preds = (const float*)d_in[0];
    const float* cls_preds = (const float*)d_in[1];
    const float* dir_preds = (const float*)d_in[2];
    const float* anchors   = (const float*)d_in[3];
    float* out = (float*)d_out;
    char* ws = (char*)d_ws;

    uint32_t* hp     = (uint32_t*)(ws + OFF_HP);
    uint32_t* counts = (uint32_t*)(ws + OFF_CNT);
    uint64_t* cand   = (uint64_t*)(ws + OFF_CAND);
    uint32_t* rankA  = (uint32_t*)(ws + OFF_RANK);

    void* args[] = { (void*)&box_preds, (void*)&cls_preds, (void*)&dir_preds,
                     (void*)&anchors, (void*)&out,
                     (void*)&hp, (void*)&counts, (void*)&cand, (void*)&rankA };
    hipLaunchCooperativeKernel((const void*)k_all, dim3(SEGS, NB), dim3(1024),
                               args, 0, stream);
}

// Round 9
// 173.039 us; speedup vs baseline: 2.5325x; 2.5325x over previous
//
#include <hip/hip_runtime.h>
#include <stdint.h>

#define NB 8
#define NN 107136
#define TOTAL (NB * NN)
#define NPAIR (NN / 2)       // 53568
#define PRE 2048
#define POST 128
#define CAP 4096
#define HBINS 128            // 16-bit key bins restricted to s in [0.5, 1)
#define KEYBASE 0xBF00u
#define SCORE_TH 0.05f
#define SH_BPB 53            // score blocks per batch (53*1024 >= 53568 pairs)
#define NSCAN 512            // boxes covered by the in-LDS suppression-bit mask

// ---------------- ws layout (bytes) ----------------
static constexpr size_t OFF_SCORES = 0;
static constexpr size_t SZ_SCORES  = (size_t)TOTAL * 4;
static constexpr size_t OFF_GHIST  = OFF_SCORES + SZ_SCORES;       // global 128-bin hist per batch
static constexpr size_t SZ_GHIST   = (size_t)NB * HBINS * 4;
static constexpr size_t OFF_CNT    = OFF_GHIST + SZ_GHIST;         // 8 x 64 u32 (256B apart)
static constexpr size_t SZ_CNT     = (size_t)NB * 64 * 4;
static constexpr size_t OFF_CAND   = OFF_CNT + SZ_CNT + 256;
static constexpr size_t SZ_CAND    = (size_t)NB * CAP * 8;
static constexpr size_t OFF_RANK   = OFF_CAND + SZ_CAND;           // partial rank accumulators
static constexpr size_t SZ_RANK    = (size_t)NB * CAP * 4;
static constexpr size_t OFF_SELS   = OFF_RANK + SZ_RANK;
static constexpr size_t OFF_SELI   = OFF_SELS + (size_t)NB * PRE * 4;
static constexpr size_t OFF_SELB   = OFF_SELI + (size_t)NB * PRE * 4;
static constexpr size_t OFF_SBB    = OFF_SELB + (size_t)NB * PRE * 7 * 4;
static constexpr size_t OFF_SAR    = OFF_SBB + (size_t)NB * PRE * 4 * 4;

// ---------------- kernels ----------------

// fused softmax scores + global 128-bin histogram (atomicAdd; ghist pre-zeroed by memset)
// + zero cand (blocks 0..15) and rankArr (blocks 16..31)
__global__ void __launch_bounds__(256) k_scoreshist(const float* __restrict__ cls,
                                                    float* __restrict__ scores,
                                                    uint32_t* __restrict__ ghist,
                                                    uint64_t* __restrict__ cand,
                                                    uint32_t* __restrict__ rankArr) {
    int b = blockIdx.y;
    int t = threadIdx.x;
    if (blockIdx.x < 16)                       // zero-pad cand (rank padding)
        cand[(size_t)b * CAP + blockIdx.x * 256 + t] = 0ull;
    else if (blockIdx.x < 32)                  // zero rank accumulators
        rankArr[(size_t)b * CAP + (blockIdx.x - 16) * 256 + t] = 0u;
    __shared__ uint32_t lh[HBINS];
    if (t < HBINS) lh[t] = 0u;
    __syncthreads();
    const float4* cp = (const float4*)cls + (size_t)b * NPAIR;
    float2* sp = (float2*)scores + (size_t)b * NPAIR;
#pragma unroll
    for (int k = 0; k < 4; k++) {
        int p = blockIdx.x * 1024 + k * 256 + t;
        if (p < NPAIR) {
            float4 c = cp[p];
            float m0 = fmaxf(c.x, c.y);
            float s0 = __fdiv_rn(expf(__fsub_rn(c.y, m0)),
                                 __fadd_rn(expf(__fsub_rn(c.x, m0)), expf(__fsub_rn(c.y, m0))));
            float m1 = fmaxf(c.z, c.w);
            float s1 = __fdiv_rn(expf(__fsub_rn(c.w, m1)),
                                 __fadd_rn(expf(__fsub_rn(c.z, m1)), expf(__fsub_rn(c.w, m1))));
            sp[p] = make_float2(s0, s1);
            if (s0 >= 0.5f) {
                uint32_t bin = ((__float_as_uint(s0) >> 16) | 0x8000u) - KEYBASE;
                if (bin > 127u) bin = 127u;
                atomicAdd(&lh[bin], 1u);
            }
            if (s1 >= 0.5f) {
                uint32_t bin = ((__float_as_uint(s1) >> 16) | 0x8000u) - KEYBASE;
                if (bin > 127u) bin = 127u;
                atomicAdd(&lh[bin], 1u);
            }
        }
    }
    __syncthreads();
    if (t < HBINS && lh[t]) atomicAdd(&ghist[(size_t)b * HBINS + t], lh[t]);
}

// compact with inline per-wave threshold-find (direct global hist: 2 loads/lane)
__global__ void __launch_bounds__(256) k_compact(const float* __restrict__ scores,
                                                 const uint32_t* __restrict__ ghist,
                                                 uint32_t* __restrict__ counts,
                                                 uint64_t* __restrict__ cand) {
    int g2 = blockIdx.x * 256 + threadIdx.x;      // pair index; grid exact
    int lane = threadIdx.x & 63, wid = threadIdx.x >> 6;
    int e0 = 2 * g2;
    int b = e0 / NN;                              // wave-uniform (NN % 128 == 0)

    // ---- wave-redundant findT over global hist (cheap: 2 loads) ----
    const uint32_t* gh = ghist + (size_t)b * HBINS;
    uint32_t h0 = gh[2 * lane];
    uint32_t h1 = gh[2 * lane + 1];
    uint32_t v = h0 + h1;
    for (int off = 1; off < 64; off <<= 1) {
        uint32_t u = __shfl_down(v, off);
        if (lane + off >= 64) u = 0u;
        v += u;
    }
    uint32_t total = __shfl(v, 0);
    int c = -1;
    if (v - h0 >= PRE) c = 2 * lane + 1;
    else if (v >= PRE) c = 2 * lane;
    for (int off = 32; off > 0; off >>= 1) c = max(c, __shfl_xor(c, off));
    uint32_t Tb = (total >= PRE && c >= 0) ? (KEYBASE + (uint32_t)c) : 0u;

    // ---- threshold test + block-aggregated slot reservation ----
    float2 sv = ((const float2*)scores)[g2];
    uint32_t key0 = __float_as_uint(sv.x) | 0x80000000u;
    uint32_t key1 = __float_as_uint(sv.y) | 0x80000000u;
    bool p0 = (sv.x >= SCORE_TH) && ((key0 >> 16) >= Tb);
    bool p1 = (sv.y >= SCORE_TH) && ((key1 >> 16) >= Tb);
    uint64_t bal0 = __ballot(p0), bal1 = __ballot(p1);
    uint32_t n0 = (uint32_t)__popcll(bal0);
    uint32_t wcnt = n0 + (uint32_t)__popcll(bal1);
    uint64_t below = (1ull << lane) - 1ull;
    uint32_t off0 = (uint32_t)__popcll(bal0 & below);
    uint32_t off1 = n0 + (uint32_t)__popcll(bal1 & below);
    __shared__ uint32_t lcnt[2];
    __shared__ uint32_t gbase[2];
    __shared__ uint32_t wbase[4];
    int b0 = (blockIdx.x * 512) / NN;
    if (threadIdx.x < 2) lcnt[threadIdx.x] = 0u;
    __syncthreads();
    if (lane == 0 && wcnt) wbase[wid] = atomicAdd(&lcnt[b - b0], wcnt);
    __syncthreads();
    if (threadIdx.x < 2 && lcnt[threadIdx.x])
        gbase[threadIdx.x] = atomicAdd(&counts[(size_t)(b0 + threadIdx.x) * 64], lcnt[threadIdx.x]);
    __syncthreads();
    if (p0 | p1) {
        uint32_t base = gbase[b - b0] + wbase[wid];
        if (p0) {
            uint32_t slot = base + off0;
            if (slot < CAP)
                cand[(size_t)b * CAP + slot] =
                    ((uint64_t)key0 << 32) | (uint64_t)(0xFFFFFFFFu - (uint32_t)(e0 - b * NN));
        }
        if (p1) {
            uint32_t slot = base + off1;
            if (slot < CAP)
                cand[(size_t)b * CAP + slot] =
                    ((uint64_t)key1 << 32) | (uint64_t)(0xFFFFFFFFu - (uint32_t)(e0 + 1 - b * NN));
        }
    }
}

// partial rank: block (ib, jt, b) ranks 256 candidates against one 512-key j-tile.
__global__ void __launch_bounds__(256) k_rank_part(const uint64_t* __restrict__ cand,
                                                   const uint32_t* __restrict__ counts,
                                                   uint32_t* __restrict__ rankArr) {
    int b = blockIdx.z;
    int m = (int)counts[(size_t)b * 64]; if (m > CAP) m = CAP;
    int i0 = blockIdx.x * 256;
    int jb = blockIdx.y * 512;
    if (i0 >= m || jb >= m) return;               // block-uniform exit
    int t = threadIdx.x;
    const uint64_t* cb = cand + (size_t)b * CAP;
    uint64_t mykey = cb[i0 + t];                  // padded region is zeros: rank-neutral
    __shared__ uint64_t tile[512];
    tile[t] = cb[jb + t];
    tile[t + 256] = cb[jb + 256 + t];
    __syncthreads();
    if (i0 + t >= m) return;                      // no barriers after this point
    uint32_t rank = 0;
#pragma unroll 16
    for (int j = 0; j < 512; j++)
        rank += (tile[j] > mykey) ? 1u : 0u;
    if (rank) atomicAdd(&rankArr[(size_t)b * CAP + i0 + t], rank);
}

// gather final rank, decode boxes, scatter into sorted slots
__global__ void __launch_bounds__(256) k_decode(
        const uint64_t* __restrict__ cand, const uint32_t* __restrict__ counts,
        const uint32_t* __restrict__ rankArr,
        const float* __restrict__ box_preds, const float* __restrict__ anchors,
        float* __restrict__ selS, uint32_t* __restrict__ selI,
        float* __restrict__ selB, float* __restrict__ selBB, float* __restrict__ selA) {
    int b = blockIdx.y;
    int m = (int)counts[(size_t)b * 64]; if (m > CAP) m = CAP;
    int i = blockIdx.x * 256 + threadIdx.x;
    if (i >= m) return;
    uint32_t rank = rankArr[(size_t)b * CAP + i];
    if (rank >= PRE) return;
    uint64_t mykey = cand[(size_t)b * CAP + i];

    size_t o = (size_t)b * PRE + rank;
    uint32_t key = (uint32_t)(mykey >> 32);
    uint32_t idx = 0xFFFFFFFFu - (uint32_t)(mykey & 0xFFFFFFFFull);
    float score = __uint_as_float(key & 0x7FFFFFFFu);
    const float* bp = box_preds + ((size_t)b * NN + idx) * 7;
    const float* an = anchors + ((size_t)b * NN + idx) * 7;
    float xa = an[0], ya = an[1], za = an[2], wa = an[3], la = an[4], ha = an[5], ra = an[6];
    float xt = bp[0], yt = bp[1], zt = bp[2], wt = bp[3], lt = bp[4], ht = bp[5], rt = bp[6];
    float za2  = __fadd_rn(za, __fmul_rn(ha, 0.5f));
    float diag = sqrtf(__fadd_rn(__fmul_rn(la, la), __fmul_rn(wa, wa)));
    float xg = __fadd_rn(__fmul_rn(xt, diag), xa);
    float yg = __fadd_rn(__fmul_rn(yt, diag), ya);
    float zg = __fadd_rn(__fmul_rn(zt, ha), za2);
    float lg = __fmul_rn(expf(lt), la);
    float wg = __fmul_rn(expf(wt), wa);
    float hg = __fmul_rn(expf(ht), ha);
    float rg = __fadd_rn(rt, ra);
    zg = __fsub_rn(zg, __fmul_rn(hg, 0.5f));
    selS[o] = score; selI[o] = idx;
    selB[o * 7 + 0] = xg; selB[o * 7 + 1] = yg; selB[o * 7 + 2] = zg;
    selB[o * 7 + 3] = wg; selB[o * 7 + 4] = lg; selB[o * 7 + 5] = hg;
    selB[o * 7 + 6] = rg;
    float cc = fabsf(cosf(rg)), ss = fabsf(sinf(rg));
    float hx = __fmul_rn(0.5f, __fadd_rn(__fmul_rn(wg, cc), __fmul_rn(lg, ss)));
    float hy = __fmul_rn(0.5f, __fadd_rn(__fmul_rn(wg, ss), __fmul_rn(lg, cc)));
    float x1 = __fsub_rn(xg, hx), y1 = __fsub_rn(yg, hy);
    float x2 = __fadd_rn(xg, hx), y2 = __fadd_rn(yg, hy);
    selBB[o * 4 + 0] = x1; selBB[o * 4 + 1] = y1;
    selBB[o * 4 + 2] = x2; selBB[o * 4 + 3] = y2;
    selA[o] = __fmul_rn(__fsub_rn(x2, x1), __fsub_rn(y2, y1));
}

// fused greedy NMS: stage boxes in LDS, build 512x512 suppression-bit mask in LDS
// (8 waves in parallel), wave-0 bit-scan (register/ballot only), serial-IoU fallback
// past NSCAN, finalize. One block per batch, 512 threads.
__global__ void __launch_bounds__(512) k_nms(
        const float* __restrict__ selBB, const float* __restrict__ selA,
        const float* __restrict__ selS, const uint32_t* __restrict__ selI,
        const float* __restrict__ selB, const uint32_t* __restrict__ counts,
        const float* __restrict__ dir_preds, float* __restrict__ out) {
    int b = blockIdx.x;
    int t = threadIdx.x;
    int lane = t & 63, wid = t >> 6;
    __shared__ float4 sbb[PRE];        // 32 KiB
    __shared__ float  sar[PRE];        // 8 KiB
    __shared__ uint64_t smask[NSCAN * 8];  // 32 KiB
    __shared__ int keptIdx[POST];
    __shared__ int keptCountSh;
    int Mv = (int)counts[(size_t)b * 64]; if (Mv > PRE) Mv = PRE;
    int lim = (Mv < NSCAN) ? Mv : NSCAN;
    const float4* bb4 = (const float4*)selBB + (size_t)b * PRE;
    const float*  ar  = selA + (size_t)b * PRE;
    for (int i = t; i < PRE; i += 512) {   // rows >= Mv are poison but never read
        sbb[i] = bb4[i];
        sar[i] = ar[i];
    }
    __syncthreads();

    // build suppression-bit mask: row i word wd, bit l = (j>i) && IoU>0.5, j=wd*64+l
    for (int i = wid; i < lim; i += 8) {
        float4 ci = sbb[i]; float ai = sar[i];
#pragma unroll
        for (int wd = 0; wd < 8; wd++) {
            int j = wd * 64 + lane;            // poison for j >= Mv: bits never tested
            float4 cj = sbb[j]; float aj = sar[j];
            float ix = fmaxf(0.f, __fsub_rn(fminf(ci.z, cj.z), fmaxf(ci.x, cj.x)));
            float iy = fmaxf(0.f, __fsub_rn(fminf(ci.w, cj.w), fmaxf(ci.y, cj.y)));
            float inter = __fmul_rn(ix, iy);
            float den = fmaxf(__fsub_rn(__fadd_rn(ai, aj), inter), 1e-8f);
            bool sup = (j > i) && (inter > __fmul_rn(0.5f, den));
            uint64_t bal = __ballot(sup);
            if (lane == 0) smask[i * 8 + wd] = bal;
        }
    }
    __syncthreads();

    // wave-0 bit-scan over the mask window (register/ballot only)
    if (t < 64) {
        uint64_t removedW = 0ull;              // lane w<8 holds removed-bits word w
        int kc = 0, i = 0;
        for (; i < lim && kc < POST; i++) {
            uint64_t mrow = (lane < 8) ? smask[i * 8 + lane] : 0ull;
            int word = i >> 6;
            bool mybit = (lane == word) && (((removedW >> (i & 63)) & 1ull) != 0ull);
            if (__ballot(mybit) == 0ull) {     // alive -> keep
                if (lane == 0) keptIdx[kc] = i;
                kc++;
                removedW |= mrow;              // suppress later boxes
            }
        }
        // fallback past the mask window (rare; direct IoU, exact greedy semantics)
        if (kc < POST && Mv > NSCAN) {
            float ax1 = 1e30f, ay1 = 1e30f, ax2 = 1e30f, ay2 = 1e30f, aar = 0.f;
            float bx1 = 1e30f, by1 = 1e30f, bx2 = 1e30f, by2 = 1e30f, bar = 0.f;
            if (lane < kc) {
                int ki = keptIdx[lane]; float4 c = sbb[ki];
                ax1 = c.x; ay1 = c.y; ax2 = c.z; ay2 = c.w; aar = sar[ki];
            }
            if (lane + 64 < kc) {
                int ki = keptIdx[lane + 64]; float4 c = sbb[ki];
                bx1 = c.x; by1 = c.y; bx2 = c.z; by2 = c.w; bar = sar[ki];
            }
            for (; i < Mv && kc < POST; i++) {
                float4 c = sbb[i];
                float ca = sar[i];
                float ix = fmaxf(0.f, __fsub_rn(fminf(ax2, c.z), fmaxf(ax1, c.x)));
                float iy = fmaxf(0.f, __fsub_rn(fminf(ay2, c.w), fmaxf(ay1, c.y)));
                float inter = __fmul_rn(ix, iy);
                float den = fmaxf(__fsub_rn(__fadd_rn(aar, ca), inter), 1e-8f);
                bool sup = inter > __fmul_rn(0.5f, den);
                ix = fmaxf(0.f, __fsub_rn(fminf(bx2, c.z), fmaxf(bx1, c.x)));
                iy = fmaxf(0.f, __fsub_rn(fminf(by2, c.w), fmaxf(by1, c.y)));
                inter = __fmul_rn(ix, iy);
                den = fmaxf(__fsub_rn(__fadd_rn(bar, ca), inter), 1e-8f);
                sup = sup || (inter > __fmul_rn(0.5f, den));
                if (__ballot(sup) == 0ull) {
                    if (lane == 0) keptIdx[kc] = i;
                    if (kc < 64) {
                        if (lane == kc) { ax1 = c.x; ay1 = c.y; ax2 = c.z; ay2 = c.w; aar = ca; }
                    } else {
                        if (lane == kc - 64) { bx1 = c.x; by1 = c.y; bx2 = c.z; by2 = c.w; bar = ca; }
                    }
                    kc++;
                }
            }
        }
        if (lane == 0) keptCountSh = kc;
    }
    __syncthreads();

    int kc = keptCountSh;
    if (t < POST) {
        size_t ob = (size_t)b * POST + t;
        float box[7] = {0.f, 0.f, 0.f, 0.f, 0.f, 0.f, 0.f};
        float sc = 0.f, mk = 0.f;
        if (t < kc) {
            int i = keptIdx[t];
            size_t o = (size_t)b * PRE + i;
            float s = selS[o];
            uint32_t idx = selI[o];
            const float* bx = selB + o * 7;
            float d0 = dir_preds[((size_t)b * NN + idx) * 2 + 0];
            float d1 = dir_preds[((size_t)b * NN + idx) * 2 + 1];
            float label = (d1 > d0) ? 1.0f : 0.0f;
            const float period = 3.14159265358979323846f;
            float r = bx[6];
            float dir_rot = __fsub_rn(r, __fmul_rn(floorf(__fdiv_rn(r, period)), period));
            float nr = __fadd_rn(dir_rot, __fmul_rn(period, label));
            float x = bx[0], y = bx[1], z = bx[2];
            bool in_range = (x >= 0.0f) && (y >= -39.68f) && (z >= -5.0f) &&
                            (x <= 69.12f) && (y <= 39.68f) && (z <= 5.0f);
            if (in_range) {
                box[0] = x; box[1] = y; box[2] = z;
                box[3] = bx[3]; box[4] = bx[4]; box[5] = bx[5]; box[6] = nr;
                sc = s; mk = 1.f;
            }
        }
        float* out_b = out;
        float* out_s = out + 7168;
        float* out_l = out + 8192;
        float* out_m = out + 9216;
        for (int c = 0; c < 7; c++) out_b[ob * 7 + c] = box[c];
        out_s[ob] = sc;
        out_l[ob] = 0.f;
        out_m[ob] = mk;
    }
}

extern "C" void kernel_launch(void* const* d_in, const int* in_sizes, int n_in,
                              void* d_out, int out_size, void* d_ws, size_t ws_size,
                              hipStream_t stream) {
    const float* box_preds = (const float*)d_in[0];
    const float* cls_preds = (const float*)d_in[1];
    const float* dir_preds = (const float*)d_in[2];
    const float* anchors   = (const float*)d_in[3];
    float* out = (float*)d_out;
    char* ws = (char*)d_ws;

    float*    scores = (float*)(ws + OFF_SCORES);
    uint32_t* ghist  = (uint32_t*)(ws + OFF_GHIST);
    uint32_t* counts = (uint32_t*)(ws + OFF_CNT);
    uint64_t* cand   = (uint64_t*)(ws + OFF_CAND);
    uint32_t* rankA  = (uint32_t*)(ws + OFF_RANK);
    float*    selS   = (float*)(ws + OFF_SELS);
    uint32_t* selI   = (uint32_t*)(ws + OFF_SELI);
    float*    selB   = (float*)(ws + OFF_SELB);
    float*    selBB  = (float*)(ws + OFF_SBB);
    float*    selA   = (float*)(ws + OFF_SAR);

    // zero ghist + counts (contiguous, 6 KiB) — graph-capture safe
    hipMemsetAsync(ws + OFF_GHIST, 0, SZ_GHIST + SZ_CNT, stream);

    dim3 gSH(SH_BPB, NB);
    k_scoreshist<<<gSH, 256, 0, stream>>>(cls_preds, scores, ghist, cand, rankA);
    k_compact<<<TOTAL / 512, 256, 0, stream>>>(scores, ghist, counts, cand);
    dim3 gRank(CAP / 256, CAP / 512, NB);
    k_rank_part<<<gRank, 256, 0, stream>>>(cand, counts, rankA);
    dim3 gDec(CAP / 256, NB);
    k_decode<<<gDec, 256, 0, stream>>>(cand, counts, rankA, box_preds, anchors,
                                       selS, selI, selB, selBB, selA);
    k_nms<<<NB, 512, 0, stream>>>(selBB, selA, selS, selI, selB, counts,
                                  dir_preds, out);
}